// Round 14
// baseline (335.817 us; speedup 1.0000x reference)
//
#include <hip/hip_runtime.h>
#include <math.h>

// Problem constants (from reference)
#define KN    20000   // vocab
#define KH    40      // LSTM hidden
#define KDW   128     // W_down width
#define KND   16      // noise dim
#define KRW   8       // rw_len
#define KNS   512     // n_sample
#define KCH   79      // ceil(KN / 256) chunks of 256 cols
#define KEPS  1e-20f
#define KLN2  0.69314718055994531f
#define NINF  (-__builtin_inff())

typedef float floatx4 __attribute__((ext_vector_type(4)));

__device__ __forceinline__ float sigmoidf_(float x) { return 1.0f / (1.0f + expf(-x)); }

// pack (score, col) into a monotone-increasing u64 key; larger = better.
// ties on score -> smaller col wins (low field = ~col).
__device__ __forceinline__ unsigned long long packsc_(float v, int col) {
  unsigned u = __float_as_uint(v);
  unsigned key = (u >> 31) ? ~u : (u | 0x80000000u);
  return ((unsigned long long)key << 32) | (unsigned)(~col);
}
// Gumbel(0,1) from uniform u — identical op DAG everywhere it's used.
__device__ __forceinline__ float gumbel_(float u) {
  float t = fmaf(-KLN2, __log2f(u + KEPS), KEPS);   // -ln(u+eps)+eps
  return -KLN2 * __log2f(t);                         // -ln(.)
}

// -------- merged: init MLP+LSTM0 (blocks 0..511) | wnorm partials (blocks 512..590) --------
__global__ void __launch_bounds__(256) k_init_wnorm(
    const float* __restrict__ z,
    const float* __restrict__ l1w, const float* __restrict__ l1b,
    const float* __restrict__ l2w, const float* __restrict__ l2b,
    const float* __restrict__ l3w, const float* __restrict__ l3b,
    const float* __restrict__ b_ih, const float* __restrict__ b_hh,
    const float* __restrict__ w_hh, const float* __restrict__ W_up,
    float* __restrict__ h, float* __restrict__ c, float* __restrict__ wpart) {
  int tid = threadIdx.x;
  __shared__ float zs[KND], inter[KH], h0[KH], c0[KH], g[4*KH];
  __shared__ float wm[4];
  if (blockIdx.x >= KNS) {
    int b = blockIdx.x - KNS;
    int j = b*256 + tid;
    int lane = tid & 63, grp = tid >> 6;
    float ss = 0.f;
    if (j < KN) {
#pragma unroll
      for (int k = 0; k < KH; ++k) { float w = W_up[k*KN + j]; ss = fmaf(w, w, ss); }
    }
    float wn = sqrtf(ss);
#pragma unroll
    for (int d = 32; d > 0; d >>= 1) wn = fmaxf(wn, __shfl_xor(wn, d, 64));
    if (lane == 0) wm[grp] = wn;
    __syncthreads();
    if (tid == 0) wpart[b] = fmaxf(fmaxf(wm[0], wm[1]), fmaxf(wm[2], wm[3]));
    return;
  }
  // ---- init part ----
  int s = blockIdx.x;
  if (tid < KND) zs[tid] = z[s*KND + tid];
  __syncthreads();
  if (tid < KH) {
    float a = l1b[tid];
#pragma unroll
    for (int k = 0; k < KND; ++k) a = fmaf(zs[k], l1w[k*KH + tid], a);
    inter[tid] = tanhf(a);
  }
  __syncthreads();
  if (tid < KH) {
    float a2 = l2b[tid], a3 = l3b[tid];
#pragma unroll
    for (int k = 0; k < KH; ++k) {
      float iv = inter[k];
      a2 = fmaf(iv, l2w[k*KH + tid], a2);
      a3 = fmaf(iv, l3w[k*KH + tid], a3);
    }
    h0[tid] = tanhf(a2);
    c0[tid] = tanhf(a3);
  }
  __syncthreads();
  if (tid < 4*KH) {
    float a = b_ih[tid] + b_hh[tid];          // x0 = 0 -> no w_ih term
#pragma unroll 8
    for (int k = 0; k < KH; ++k) a = fmaf(h0[k], w_hh[k*4*KH + tid], a);
    g[tid] = a;
  }
  __syncthreads();
  if (tid < KH) {
    float gi = g[tid], gf = g[KH+tid], gg = g[2*KH+tid], go = g[3*KH+tid];
    float cn = sigmoidf_(gf) * c0[tid] + sigmoidf_(gi) * tanhf(gg);
    float hn = sigmoidf_(go) * tanhf(cn);
    h[s*KH + tid] = hn;
    c[s*KH + tid] = cn;
  }
}

// -------- MEGA kernel: block = sample (1024 threads = 16 waves). Per block:
//   A : stream-score all 8 gu rows -> LDS chunk maxima (80KB/row, 5 float4/thr)
//   A2: NT zero-fill the sample's 8 out rows (barrier drains before spikes)
//   B : 8-step resolve: threshold+cand (wave0 ballot) -> pruned exact rescan
//       (rows L2/L3-warm) -> spike -> LSTM advance. No pp global round-trip. --------
__global__ void __launch_bounds__(1024) k_mega(
    const float* __restrict__ gu,           // [RW][NS][KN]
    const float* __restrict__ b_up,         // [KN]
    const float* __restrict__ W_up,         // [KH][KN]
    const float* __restrict__ wpart,        // [KCH]
    const float* __restrict__ hg, const float* __restrict__ cg,
    const float* __restrict__ W_down,
    const float* __restrict__ w_ih, const float* __restrict__ w_hh,
    const float* __restrict__ b_ih, const float* __restrict__ b_hh,
    float* __restrict__ out) {              // [NS][RW][KN]
  int s = blockIdx.x;
  int tid = threadIdx.x, wave = tid >> 6, lane = tid & 63;
  __shared__ float ppl[KRW*KCH];            // 632 f
  __shared__ float hs[KH], cs[KH], xs[KDW], g[4*KH];
  __shared__ float sThr;
  __shared__ int cand[KCH], ncandS, widxS;
  __shared__ unsigned long long wbest[16];

  if (tid < KH) { hs[tid] = hg[s*KH + tid]; cs[tid] = cg[s*KH + tid]; }

  // ---- phase A: score all 8 rows into LDS ----
  for (int t = 0; t < KRW; ++t) {
    const float* urow = gu + ((size_t)t*KNS + s)*KN;
    floatx4 u4[5];
#pragma unroll
    for (int k = 0; k < 5; ++k) {
      int i = tid + k*1024;                  // float4 index, 5000 per row
      u4[k] = *((const floatx4*)urow + (i < 5000 ? i : 4999));
    }
    float m[5];
#pragma unroll
    for (int k = 0; k < 5; ++k) {
      int i = tid + k*1024;
      bool v = i < 5000;
      floatx4 b4 = *((const floatx4*)b_up + (v ? i : 0));   // L2-resident
      float k0 = gumbel_(u4[k][0]) + b4[0];
      float k1 = gumbel_(u4[k][1]) + b4[1];
      float k2 = gumbel_(u4[k][2]) + b4[2];
      float k3 = gumbel_(u4[k][3]) + b4[3];
      m[k] = v ? fmaxf(fmaxf(k0, k1), fmaxf(k2, k3)) : NINF;
    }
#pragma unroll
    for (int d = 32; d > 0; d >>= 1) {
#pragma unroll
      for (int k = 0; k < 5; ++k)
        m[k] = fmaxf(m[k], __shfl_xor(m[k], d, 64));
    }
    if (lane == 0) {
#pragma unroll
      for (int k = 0; k < 5; ++k) {
        int ch = wave + 16*k;                // i>>6 for this wave/k
        if (ch < KCH) ppl[t*KCH + ch] = m[k];
      }
    }
  }

  // ---- phase A2: NT zero-fill this sample's 8 out rows ----
  floatx4 zv = (floatx4)(0.f);
  for (int t = 0; t < KRW; ++t) {
    float* orow = out + ((size_t)s*KRW + t)*KN;
#pragma unroll
    for (int k = 0; k < 5; ++k) {
      int i = tid + k*1024;
      if (i < 5000) __builtin_nontemporal_store(zv, (floatx4*)orow + i);
    }
  }
  __syncthreads();   // ppl visible to all; vmcnt(0) drain orders NT zeros before spikes

  // ---- wave0-resident wnm, ||h|| ----
  float wnm = 0.f, hn = 0.f;
  if (wave == 0) {
    float a = (lane < KCH) ? wpart[lane] : NINF;
    float b = (lane + 64 < KCH) ? wpart[lane + 64] : NINF;
    float mm = fmaxf(a, b);
#pragma unroll
    for (int d = 32; d > 0; d >>= 1) mm = fmaxf(mm, __shfl_xor(mm, d, 64));
    wnm = mm;
    float x = (lane < KH) ? hs[lane] : 0.f;
    float vv = x * x;
#pragma unroll
    for (int d = 32; d > 0; d >>= 1) vv += __shfl_xor(vv, d, 64);
    hn = sqrtf(vv);
  }

  // ---- phase B: 8-step resolve ----
  for (int t = 0; t < KRW; ++t) {
    if (wave == 0) {
      const float* pt = ppl + t*KCH;
      float a = pt[lane];
      float b = (lane + 64 < KCH) ? pt[lane + 64] : NINF;
      float mm = fmaxf(a, b);
#pragma unroll
      for (int d = 32; d > 0; d >>= 1) mm = fmaxf(mm, __shfl_xor(mm, d, 64));
      float thr = mm - 2.0f * (hn * wnm * 1.001f + 1e-4f);  // safe |h.w_j| bound
      bool c0 = a >= thr;
      bool c1 = (lane + 64 < KCH) && (b >= thr);
      unsigned long long m0 = __ballot(c0), m1 = __ballot(c1);
      unsigned long long lm = ((1ull << lane) - 1ull);
      if (c0) cand[__popcll(m0 & lm)] = lane;
      if (c1) cand[__popcll(m0) + __popcll(m1 & lm)] = lane + 64;
      if (lane == 0) { ncandS = (int)(__popcll(m0) + __popcll(m1)); sThr = thr; }
    }
    __syncthreads();                                   // sync 1: cand/thr/hs published
    int nc = ncandS;
    float thr = sThr;
    unsigned long long best = 0ull;
    const float* urow = gu + ((size_t)t*KNS + s)*KN;
    for (int ci = (tid >> 8); ci < nc; ci += 4) {      // 4 candidates in parallel
      int col = cand[ci]*256 + (tid & 255);
      if (col < KN) {
        float key = gumbel_(urow[col]) + b_up[col];    // identical DAG to phase A
        if (key >= thr) {
          float sc = key;
#pragma unroll
          for (int k = 0; k < KH; ++k) sc = fmaf(hs[k], W_up[k*KN + col], sc);
          unsigned long long pk = packsc_(sc, col);
          if (pk > best) best = pk;
        }
      }
    }
#pragma unroll
    for (int d = 32; d > 0; d >>= 1) {
      unsigned long long q = (unsigned long long)__shfl_xor((long long)best, d, 64);
      if (q > best) best = q;
    }
    if (lane == 0) wbest[wave] = best;
    __syncthreads();                                   // sync 2: per-wave bests
    if (wave == 0) {
      unsigned long long b2 = (lane < 16) ? wbest[lane] : 0ull;
#pragma unroll
      for (int d = 8; d > 0; d >>= 1) {
        unsigned long long q = (unsigned long long)__shfl_xor((long long)b2, d, 64);
        if (q > b2) b2 = q;
      }
      if (lane == 0) {
        int w = (int)(~(unsigned)(b2 & 0xFFFFFFFFull));
        widxS = w;
        out[((size_t)s*KRW + t)*KN + w] = 1.0f;        // spike (zeros drained at barrier)
      }
    }
    __syncthreads();                                   // sync 3: widx published
    if (t < KRW - 1) {
      if (tid < KDW) xs[tid] = W_down[(size_t)widxS*KDW + tid];
      __syncthreads();                                 // sync 4: xs ready
      if (tid < 4*KH) {
        float a = b_ih[tid] + b_hh[tid];
#pragma unroll 8
        for (int k = 0; k < KDW; ++k) a = fmaf(xs[k], w_ih[k*4*KH + tid], a);
#pragma unroll 8
        for (int k = 0; k < KH; ++k) a = fmaf(hs[k], w_hh[k*4*KH + tid], a);
        g[tid] = a;
      }
      __syncthreads();                                 // sync 5: gates ready
      if (tid < KH) {                                  // tid<40 -> all in wave0
        float gi = g[tid], gf = g[KH+tid], gg2 = g[2*KH+tid], go = g[3*KH+tid];
        float cn = sigmoidf_(gf) * cs[tid] + sigmoidf_(gi) * tanhf(gg2);
        float hn_ = sigmoidf_(go) * tanhf(cn);
        hs[tid] = hn_; cs[tid] = cn;
      }
      if (wave == 0) {                                 // within-wave LDS ordering ok
        float x = (lane < KH) ? hs[lane] : 0.f;
        float vv = x * x;
#pragma unroll
        for (int d = 32; d > 0; d >>= 1) vv += __shfl_xor(vv, d, 64);
        hn = sqrtf(vv);
      }
      // other waves read updated hs after next iter's sync 1
    }
  }
}

extern "C" void kernel_launch(void* const* d_in, const int* in_sizes, int n_in,
                              void* d_out, int out_size, void* d_ws, size_t ws_size,
                              hipStream_t stream) {
  const float* z      = (const float*)d_in[0];
  const float* gu     = (const float*)d_in[1];
  const float* l1w    = (const float*)d_in[2];
  const float* l1b    = (const float*)d_in[3];
  const float* l2w    = (const float*)d_in[4];
  const float* l2b    = (const float*)d_in[5];
  const float* l3w    = (const float*)d_in[6];
  const float* l3b    = (const float*)d_in[7];
  const float* w_ih   = (const float*)d_in[8];
  const float* w_hh   = (const float*)d_in[9];
  const float* b_ih   = (const float*)d_in[10];
  const float* b_hh   = (const float*)d_in[11];
  const float* W_up   = (const float*)d_in[12];
  const float* b_up   = (const float*)d_in[13];
  const float* W_down = (const float*)d_in[14];
  float* out = (float*)d_out;

  // workspace: h, c, wpart only (all rewritten each call)
  char* ws = (char*)d_ws;
  float* h  = (float*)(ws);                                    // 512*40 f32
  float* c  = (float*)(ws + (size_t)KNS*KH*4);                 // 512*40 f32
  float* wpart = (float*)(ws + (size_t)2*KNS*KH*4);            // 79 f32

  k_init_wnorm<<<KNS + KCH, 256, 0, stream>>>(z, l1w, l1b, l2w, l2b, l3w, l3b,
                                              b_ih, b_hh, w_hh, W_up, h, c, wpart);

  k_mega<<<KNS, 1024, 0, stream>>>(gu, b_up, W_up, wpart, h, c,
                                   W_down, w_ih, w_hh, b_ih, b_hh, out);
}

// Round 15
// 269.433 us; speedup vs baseline: 1.2464x; 1.2464x over previous
//
#include <hip/hip_runtime.h>
#include <math.h>

// Problem constants (from reference)
#define KN    20000   // vocab
#define KH    40      // LSTM hidden
#define KDW   128     // W_down width
#define KND   16      // noise dim
#define KRW   8       // rw_len
#define KNS   512     // n_sample
#define KCH   79      // chunks of 256 floats per row (78 full + 32-float tail)
#define NSEG  (KRW*KNS*KCH)                  // 323,584 wave-segments
#define KEPS  1e-20f
#define KLN2  0.69314718055994531f
#define NINF  (-__builtin_inff())

typedef float floatx4 __attribute__((ext_vector_type(4)));

__device__ __forceinline__ float sigmoidf_(float x) { return 1.0f / (1.0f + expf(-x)); }

__device__ __forceinline__ unsigned long long packsc_(float v, int col) {
  unsigned u = __float_as_uint(v);
  unsigned key = (u >> 31) ? ~u : (u | 0x80000000u);
  return ((unsigned long long)key << 32) | (unsigned)(~col);
}
// Gumbel(0,1) from uniform u — identical op DAG everywhere it's used.
__device__ __forceinline__ float gumbel_(float u) {
  float t = fmaf(-KLN2, __log2f(u + KEPS), KEPS);   // -ln(u+eps)+eps
  return -KLN2 * __log2f(t);                         // -ln(.)
}

// -------- merged: init MLP+LSTM0 (blocks 0..511) | wnorm partials (blocks 512..590) --------
__global__ void __launch_bounds__(256) k_init_wnorm(
    const float* __restrict__ z,
    const float* __restrict__ l1w, const float* __restrict__ l1b,
    const float* __restrict__ l2w, const float* __restrict__ l2b,
    const float* __restrict__ l3w, const float* __restrict__ l3b,
    const float* __restrict__ b_ih, const float* __restrict__ b_hh,
    const float* __restrict__ w_hh, const float* __restrict__ W_up,
    float* __restrict__ h, float* __restrict__ c, float* __restrict__ wpart) {
  int tid = threadIdx.x;
  __shared__ float zs[KND], inter[KH], h0[KH], c0[KH], g[4*KH];
  __shared__ float wm[4];
  if (blockIdx.x >= KNS) {
    int b = blockIdx.x - KNS;
    int j = b*256 + tid;
    int lane = tid & 63, grp = tid >> 6;
    float ss = 0.f;
    if (j < KN) {
#pragma unroll
      for (int k = 0; k < KH; ++k) { float w = W_up[k*KN + j]; ss = fmaf(w, w, ss); }
    }
    float wn = sqrtf(ss);
#pragma unroll
    for (int d = 32; d > 0; d >>= 1) wn = fmaxf(wn, __shfl_xor(wn, d, 64));
    if (lane == 0) wm[grp] = wn;
    __syncthreads();
    if (tid == 0) wpart[b] = fmaxf(fmaxf(wm[0], wm[1]), fmaxf(wm[2], wm[3]));
    return;
  }
  int s = blockIdx.x;
  if (tid < KND) zs[tid] = z[s*KND + tid];
  __syncthreads();
  if (tid < KH) {
    float a = l1b[tid];
#pragma unroll
    for (int k = 0; k < KND; ++k) a = fmaf(zs[k], l1w[k*KH + tid], a);
    inter[tid] = tanhf(a);
  }
  __syncthreads();
  if (tid < KH) {
    float a2 = l2b[tid], a3 = l3b[tid];
#pragma unroll
    for (int k = 0; k < KH; ++k) {
      float iv = inter[k];
      a2 = fmaf(iv, l2w[k*KH + tid], a2);
      a3 = fmaf(iv, l3w[k*KH + tid], a3);
    }
    h0[tid] = tanhf(a2);
    c0[tid] = tanhf(a3);
  }
  __syncthreads();
  if (tid < 4*KH) {
    float a = b_ih[tid] + b_hh[tid];          // x0 = 0 -> no w_ih term
#pragma unroll 8
    for (int k = 0; k < KH; ++k) a = fmaf(h0[k], w_hh[k*4*KH + tid], a);
    g[tid] = a;
  }
  __syncthreads();
  if (tid < KH) {
    float gi = g[tid], gf = g[KH+tid], gg = g[2*KH+tid], go = g[3*KH+tid];
    float cn = sigmoidf_(gf) * c0[tid] + sigmoidf_(gi) * tanhf(gg);
    float hn = sigmoidf_(go) * tanhf(cn);
    h[s*KH + tid] = hn;
    c[s*KH + tid] = cn;
  }
}

// -------- stream kernel, fill-shaped: two compact linearly-sweeping fronts.
//  per iteration: each THREAD zero-stores one float4 at a globally consecutive
//  out position; each WAVE scores one 256-float globally consecutive gu segment
//  (segment = (row, chunk), never crosses a row) -> shuffle max -> pp[g]. --------
__global__ void __launch_bounds__(256) k_stream(
    const float* __restrict__ gu,           // [RW][NS][KN] = [4096][20000]
    const float* __restrict__ b_up,         // [KN]
    float* __restrict__ pp,                 // [RW*NS][KCH] flat = pp[g]
    float* __restrict__ out) {              // [NS][RW][KN]
  const size_t TOT4 = (size_t)KNS * KRW * KN / 4;      // 20,480,000
  int tid = threadIdx.x, wave = tid >> 6, lane = tid & 63;
  int nwaves = gridDim.x * 4;
  int wgid = blockIdx.x*4 + wave;
  size_t zpos = (size_t)blockIdx.x*256 + tid;
  size_t zstr = (size_t)gridDim.x*256;
  int g = wgid;
  floatx4 zv = (floatx4)(0.f);

  for (int it = 0; it < 40; ++it) {
    // write front: compact, consecutive threads -> consecutive addresses
    if (zpos < TOT4) __builtin_nontemporal_store(zv, (floatx4*)out + zpos);
    // read front: wave scores segment g (256 floats, within one gu row)
    if (g < NSEG) {
      int row = g / KCH;                    // t*KNS + s
      int j   = g - row*KCH;
      int f4  = j*64 + lane;                // float4 index within row (5000/row)
      bool v  = f4 < 5000;
      int f4c = v ? f4 : 4999;
      floatx4 u4 = *((const floatx4*)gu + (size_t)row*5000 + f4c);
      floatx4 b4 = *((const floatx4*)b_up + f4c);      // L2-resident
      float k0 = gumbel_(u4[0]) + b4[0];
      float k1 = gumbel_(u4[1]) + b4[1];
      float k2 = gumbel_(u4[2]) + b4[2];
      float k3 = gumbel_(u4[3]) + b4[3];
      float m = v ? fmaxf(fmaxf(k0, k1), fmaxf(k2, k3)) : NINF;
#pragma unroll
      for (int d = 32; d > 0; d >>= 1) m = fmaxf(m, __shfl_xor(m, d, 64));
      if (lane == 0) pp[g] = m;
    }
    zpos += zstr; g += nwaves;
  }
}

// ------- resolve: block = sample, loops t=0..7 (R12 structure; pp[g] layout) -------
__global__ void __launch_bounds__(256) k_resolve(
    const float* __restrict__ pp,           // [RW*NS][KCH] flat
    const float* __restrict__ gu,
    const float* __restrict__ W_up, const float* __restrict__ b_up,
    const float* __restrict__ wpart,        // [KCH]
    const float* __restrict__ hg, const float* __restrict__ cg,
    const float* __restrict__ W_down,
    const float* __restrict__ w_ih, const float* __restrict__ w_hh,
    const float* __restrict__ b_ih, const float* __restrict__ b_hh,
    float* __restrict__ out) {
  int s = blockIdx.x, tid = threadIdx.x;
  int wave = tid >> 6, lane = tid & 63;
  __shared__ float ppl[KRW*KCH];            // 632 floats
  __shared__ float hs[KH], cs[KH], xs[KDW], g[4*KH];
  __shared__ float sThr;
  __shared__ int cand[KCH], ncandS, widxS;
  __shared__ unsigned long long wbest[4];

  for (int j = tid; j < KRW*KCH; j += 256) {
    int t = j / KCH, ch = j - t*KCH;
    ppl[j] = pp[((size_t)t*KNS + s)*KCH + ch];
  }
  if (tid < KH) { hs[tid] = hg[s*KH + tid]; cs[tid] = cg[s*KH + tid]; }
  __syncthreads();

  float wnm = 0.f, hn = 0.f;                // wave0-resident
  if (wave == 0) {
    float a = (lane < KCH) ? wpart[lane] : NINF;
    float b = (lane + 64 < KCH) ? wpart[lane + 64] : NINF;
    float m = fmaxf(a, b);
#pragma unroll
    for (int d = 32; d > 0; d >>= 1) m = fmaxf(m, __shfl_xor(m, d, 64));
    wnm = m;
    float x = (lane < KH) ? hs[lane] : 0.f;
    float vv = x * x;
#pragma unroll
    for (int d = 32; d > 0; d >>= 1) vv += __shfl_xor(vv, d, 64);
    hn = sqrtf(vv);
  }

  for (int t = 0; t < KRW; ++t) {
    if (wave == 0) {
      const float* pt = ppl + t*KCH;
      float a = pt[lane];
      float b = (lane + 64 < KCH) ? pt[lane + 64] : NINF;
      float m = fmaxf(a, b);
#pragma unroll
      for (int d = 32; d > 0; d >>= 1) m = fmaxf(m, __shfl_xor(m, d, 64));
      float thr = m - 2.0f * (hn * wnm * 1.001f + 1e-4f);   // safe |h.w_j| bound
      bool c0 = a >= thr;
      bool c1 = (lane + 64 < KCH) && (b >= thr);
      unsigned long long m0 = __ballot(c0), m1 = __ballot(c1);
      unsigned long long lm = ((1ull << lane) - 1ull);
      if (c0) cand[__popcll(m0 & lm)] = lane;
      if (c1) cand[__popcll(m0) + __popcll(m1 & lm)] = lane + 64;
      if (lane == 0) { ncandS = (int)(__popcll(m0) + __popcll(m1)); sThr = thr; }
    }
    __syncthreads();                                   // sync 1
    int nc = ncandS;
    float thr = sThr;
    unsigned long long best = 0ull;
    const float* urow = gu + ((size_t)t*KNS + s)*KN;
    for (int ci = 0; ci < nc; ++ci) {
      int col = cand[ci]*256 + tid;
      if (col < KN) {
        float key = gumbel_(urow[col]) + b_up[col];    // identical DAG to k_stream
        if (key >= thr) {
          float sc = key;
#pragma unroll
          for (int k = 0; k < KH; ++k) sc = fmaf(hs[k], W_up[k*KN + col], sc);
          unsigned long long pk = packsc_(sc, col);
          if (pk > best) best = pk;
        }
      }
    }
#pragma unroll
    for (int d = 32; d > 0; d >>= 1) {
      unsigned long long q = (unsigned long long)__shfl_xor((long long)best, d, 64);
      if (q > best) best = q;
    }
    if (lane == 0) wbest[wave] = best;
    __syncthreads();                                   // sync 2
    if (tid == 0) {
      unsigned long long fb = wbest[0];
      if (wbest[1] > fb) fb = wbest[1];
      if (wbest[2] > fb) fb = wbest[2];
      if (wbest[3] > fb) fb = wbest[3];
      int w = (int)(~(unsigned)(fb & 0xFFFFFFFFull));
      widxS = w;
      out[((size_t)s*KRW + t)*KN + w] = 1.0f;          // spike (zeros laid by k_stream)
    }
    __syncthreads();                                   // sync 3
    if (t < KRW - 1) {
      if (tid < KDW) xs[tid] = W_down[(size_t)widxS*KDW + tid];
      __syncthreads();                                 // sync 4
      if (tid < 4*KH) {
        float a = b_ih[tid] + b_hh[tid];
#pragma unroll 8
        for (int k = 0; k < KDW; ++k) a = fmaf(xs[k], w_ih[k*4*KH + tid], a);
#pragma unroll 8
        for (int k = 0; k < KH; ++k) a = fmaf(hs[k], w_hh[k*4*KH + tid], a);
        g[tid] = a;
      }
      __syncthreads();                                 // sync 5
      if (tid < KH) {
        float gi = g[tid], gf = g[KH+tid], gg2 = g[2*KH+tid], go = g[3*KH+tid];
        float cn = sigmoidf_(gf) * cs[tid] + sigmoidf_(gi) * tanhf(gg2);
        float hn_ = sigmoidf_(go) * tanhf(cn);
        hs[tid] = hn_; cs[tid] = cn;
      }
      if (wave == 0) {
        float x = (lane < KH) ? hs[lane] : 0.f;
        float vv = x * x;
#pragma unroll
        for (int d = 32; d > 0; d >>= 1) vv += __shfl_xor(vv, d, 64);
        hn = sqrtf(vv);
      }
    }
  }
}

extern "C" void kernel_launch(void* const* d_in, const int* in_sizes, int n_in,
                              void* d_out, int out_size, void* d_ws, size_t ws_size,
                              hipStream_t stream) {
  const float* z      = (const float*)d_in[0];
  const float* gu     = (const float*)d_in[1];
  const float* l1w    = (const float*)d_in[2];
  const float* l1b    = (const float*)d_in[3];
  const float* l2w    = (const float*)d_in[4];
  const float* l2b    = (const float*)d_in[5];
  const float* l3w    = (const float*)d_in[6];
  const float* l3b    = (const float*)d_in[7];
  const float* w_ih   = (const float*)d_in[8];
  const float* w_hh   = (const float*)d_in[9];
  const float* b_ih   = (const float*)d_in[10];
  const float* b_hh   = (const float*)d_in[11];
  const float* W_up   = (const float*)d_in[12];
  const float* b_up   = (const float*)d_in[13];
  const float* W_down = (const float*)d_in[14];
  float* out = (float*)d_out;

  // workspace (~1.46 MB), every byte rewritten each call
  char* ws = (char*)d_ws;
  float* h  = (float*)(ws);                                    // 512*40 f32
  float* c  = (float*)(ws + (size_t)KNS*KH*4);                 // 512*40 f32
  float* pp = (float*)(ws + (size_t)2*KNS*KH*4);               // NSEG f32
  float* wpart = (float*)(ws + (size_t)2*KNS*KH*4 + (size_t)NSEG*4); // 79 f32

  k_init_wnorm<<<KNS + KCH, 256, 0, stream>>>(z, l1w, l1b, l2w, l2b, l3w, l3b,
                                              b_ih, b_hh, w_hh, W_up, h, c, wpart);

  k_stream<<<2048, 256, 0, stream>>>(gu, b_up, pp, out);

  k_resolve<<<KNS, 256, 0, stream>>>(pp, gu, W_up, b_up, wpart, h, c,
                                     W_down, w_ih, w_hh, b_ih, b_hh, out);
}

// Round 16
// 194.937 us; speedup vs baseline: 1.7227x; 1.3822x over previous
//
#include <hip/hip_runtime.h>
#include <math.h>

// Problem constants (from reference)
#define KN    20000   // vocab
#define KH    40      // LSTM hidden
#define KDW   128     // W_down width
#define KND   16      // noise dim
#define KRW   8       // rw_len
#define KNS   512     // n_sample
#define KCH   79      // chunks of 256 cols per row
#define NROW  (KRW*KNS)
#define CMAX  32      // candidate cap per row (overflow -> exact fallback)
#define KEPS  1e-20f
#define KLN2  0.69314718055994531f
#define HBND  6.32455532f   // sqrt(40): ||h|| bound (h entries are sigmoid*tanh in (-1,1))
#define NINF  (-__builtin_inff())

typedef float floatx4 __attribute__((ext_vector_type(4)));

__device__ __forceinline__ float sigmoidf_(float x) { return 1.0f / (1.0f + expf(-x)); }

// pack (score, col) into a monotone u64 key; larger = better; ties -> smaller col.
__device__ __forceinline__ unsigned long long packsc_(float v, int col) {
  unsigned u = __float_as_uint(v);
  unsigned key = (u >> 31) ? ~u : (u | 0x80000000u);
  return ((unsigned long long)key << 32) | (unsigned)(~col);
}
// Gumbel(0,1) from uniform u — identical op DAG everywhere it's used.
__device__ __forceinline__ float gumbel_(float u) {
  float t = fmaf(-KLN2, __log2f(u + KEPS), KEPS);   // -ln(u+eps)+eps
  return -KLN2 * __log2f(t);                         // -ln(.)
}

// -------- merged: init MLP+LSTM0 (blocks 0..511) | wnorm partials (blocks 512..590) --------
__global__ void __launch_bounds__(256) k_init_wnorm(
    const float* __restrict__ z,
    const float* __restrict__ l1w, const float* __restrict__ l1b,
    const float* __restrict__ l2w, const float* __restrict__ l2b,
    const float* __restrict__ l3w, const float* __restrict__ l3b,
    const float* __restrict__ b_ih, const float* __restrict__ b_hh,
    const float* __restrict__ w_hh, const float* __restrict__ W_up,
    float* __restrict__ h, float* __restrict__ c, float* __restrict__ wpart) {
  int tid = threadIdx.x;
  __shared__ float zs[KND], inter[KH], h0[KH], c0[KH], g[4*KH];
  __shared__ float wm[4];
  if (blockIdx.x >= KNS) {
    int b = blockIdx.x - KNS;
    int j = b*256 + tid;
    int lane = tid & 63, grp = tid >> 6;
    float ss = 0.f;
    if (j < KN) {
#pragma unroll
      for (int k = 0; k < KH; ++k) { float w = W_up[k*KN + j]; ss = fmaf(w, w, ss); }
    }
    float wn = sqrtf(ss);
#pragma unroll
    for (int d = 32; d > 0; d >>= 1) wn = fmaxf(wn, __shfl_xor(wn, d, 64));
    if (lane == 0) wm[grp] = wn;
    __syncthreads();
    if (tid == 0) wpart[b] = fmaxf(fmaxf(wm[0], wm[1]), fmaxf(wm[2], wm[3]));
    return;
  }
  int s = blockIdx.x;
  if (tid < KND) zs[tid] = z[s*KND + tid];
  __syncthreads();
  if (tid < KH) {
    float a = l1b[tid];
#pragma unroll
    for (int k = 0; k < KND; ++k) a = fmaf(zs[k], l1w[k*KH + tid], a);
    inter[tid] = tanhf(a);
  }
  __syncthreads();
  if (tid < KH) {
    float a2 = l2b[tid], a3 = l3b[tid];
#pragma unroll
    for (int k = 0; k < KH; ++k) {
      float iv = inter[k];
      a2 = fmaf(iv, l2w[k*KH + tid], a2);
      a3 = fmaf(iv, l3w[k*KH + tid], a3);
    }
    h0[tid] = tanhf(a2);
    c0[tid] = tanhf(a3);
  }
  __syncthreads();
  if (tid < 4*KH) {
    float a = b_ih[tid] + b_hh[tid];          // x0 = 0 -> no w_ih term
#pragma unroll 8
    for (int k = 0; k < KH; ++k) a = fmaf(h0[k], w_hh[k*4*KH + tid], a);
    g[tid] = a;
  }
  __syncthreads();
  if (tid < KH) {
    float gi = g[tid], gf = g[KH+tid], gg = g[2*KH+tid], go = g[3*KH+tid];
    float cn = sigmoidf_(gf) * c0[tid] + sigmoidf_(gi) * tanhf(gg);
    float hn = sigmoidf_(go) * tanhf(cn);
    h[s*KH + tid] = hn;
    c[s*KH + tid] = cn;
  }
}

// ------- stream (R12's best-measured form): block = one (s,t) row; 20 upfront
//         loads, chunk maxima -> pp, NT zero stores last. -------
__global__ void __launch_bounds__(256) k_score_zero(
    const float* __restrict__ gu,           // [RW][NS][KN]
    const float* __restrict__ b_up,         // [KN]
    float* __restrict__ pp,                 // [NS*RW][KCH]  (row r = s*KRW+t)
    float* __restrict__ out) {              // [NS][RW][KN]
  int s = blockIdx.x, t = blockIdx.y;
  int tid = threadIdx.x, grp = tid >> 6, lane = tid & 63;
  __shared__ float cm[KCH + 1];
  const float* urow = gu + ((size_t)t*KNS + s)*KN;
  float* orow = out + ((size_t)s*KRW + t)*KN;

  floatx4 u4[20];
#pragma unroll
  for (int it = 0; it < 20; ++it) {
    int col = (it*256 + tid) * 4;
    u4[it] = *(const floatx4*)(urow + (col < KN ? col : KN - 4));
  }
  float m[20];
#pragma unroll
  for (int it = 0; it < 20; ++it) {
    int col = (it*256 + tid) * 4;
    bool v = col < KN;
    floatx4 b4 = *(const floatx4*)(b_up + (v ? col : 0));
    float k0 = gumbel_(u4[it][0]) + b4[0];
    float k1 = gumbel_(u4[it][1]) + b4[1];
    float k2 = gumbel_(u4[it][2]) + b4[2];
    float k3 = gumbel_(u4[it][3]) + b4[3];
    m[it] = v ? fmaxf(fmaxf(k0, k1), fmaxf(k2, k3)) : NINF;
  }
#pragma unroll
  for (int d = 32; d > 0; d >>= 1) {
#pragma unroll
    for (int it = 0; it < 20; ++it)
      m[it] = fmaxf(m[it], __shfl_xor(m[it], d, 64));
  }
#pragma unroll
  for (int it = 0; it < 20; ++it) {
    int ch = it*4 + grp;
    if (lane == 0 && ch < KCH) cm[ch] = m[it];
  }
  __syncthreads();
  if (tid < KCH) pp[((size_t)s*KRW + t)*KCH + tid] = cm[tid];

  floatx4 zv = (floatx4)(0.f);
#pragma unroll
  for (int it = 0; it < 20; ++it) {
    int col = (it*256 + tid) * 4;
    if (col < KN) __builtin_nontemporal_store(zv, (floatx4*)(orow + col));
  }
}

// ------- candidate extraction, fully parallel (h-independent threshold):
//   block = row r. thr = rowmax - 2*sqrt(40)*wnmax (valid for ANY h).
//   Rescan candidate chunks, emit (key,col) list (cap CMAX, overflow -> -1). -------
__global__ void __launch_bounds__(128) k_cands(
    const float* __restrict__ pp,           // [NROW][KCH]
    const float* __restrict__ gu,
    const float* __restrict__ b_up,
    const float* __restrict__ wpart,        // [KCH]
    int2* __restrict__ candbuf,             // [NROW][CMAX]  (.x=key bits, .y=col)
    int* __restrict__ candcnt) {            // [NROW]
  int r = blockIdx.x;                       // r = s*KRW + t
  int s = r / KRW, t = r - s*KRW;
  int tid = threadIdx.x, lane = tid & 63, wave = tid >> 6;
  __shared__ float sThr;
  __shared__ int chlist[KCH], nch, ncand, ovf;
  if (tid == 0) { nch = 0; ncand = 0; ovf = 0; }
  __syncthreads();

  if (wave == 0) {
    float a = pp[(size_t)r*KCH + lane];                    // lane<64<79 valid
    float b = (lane + 64 < KCH) ? pp[(size_t)r*KCH + lane + 64] : NINF;
    float m = fmaxf(a, b);
    float wa = wpart[lane < KCH ? lane : 0];
    float wb = (lane + 64 < KCH) ? wpart[lane + 64] : NINF;
    float wm = fmaxf(wa, wb);
#pragma unroll
    for (int d = 32; d > 0; d >>= 1) {
      m  = fmaxf(m,  __shfl_xor(m,  d, 64));
      wm = fmaxf(wm, __shfl_xor(wm, d, 64));
    }
    if (lane == 0) sThr = m - (2.0f * HBND * wm * 1.001f + 1e-4f);
  }
  __syncthreads();
  float thr = sThr;
  // candidate chunks
  if (tid < KCH && pp[(size_t)r*KCH + tid] >= thr) {
    int i = atomicAdd(&nch, 1);
    chlist[i] = tid;
  }
  __syncthreads();
  int nchunks = nch;
  const float* urow = gu + ((size_t)t*KNS + s)*KN;
  for (int ci = 0; ci < nchunks; ++ci) {
    int base = chlist[ci]*256;
#pragma unroll
    for (int half = 0; half < 2; ++half) {
      int col = base + half*128 + tid;
      if (col < KN) {
        float key = gumbel_(urow[col]) + b_up[col];        // identical DAG to stream
        if (key >= thr) {
          int i = atomicAdd(&ncand, 1);
          if (i < CMAX) candbuf[(size_t)r*CMAX + i] = make_int2(__float_as_int(key), col);
          else ovf = 1;
        }
      }
    }
  }
  __syncthreads();
  if (tid == 0) candcnt[r] = ovf ? -1 : ncand;
}

// ------- final: block = sample; 8 steps of {pick best candidate via wave-parallel
//         dot, spike write, LSTM advance}. No thresholds, no gu scans (unless fallback). -------
__global__ void __launch_bounds__(256) k_final(
    const int2* __restrict__ candbuf, const int* __restrict__ candcnt,
    const float* __restrict__ gu,
    const float* __restrict__ W_up, const float* __restrict__ b_up,
    const float* __restrict__ hg, const float* __restrict__ cg,
    const float* __restrict__ W_down,
    const float* __restrict__ w_ih, const float* __restrict__ w_hh,
    const float* __restrict__ b_ih, const float* __restrict__ b_hh,
    float* __restrict__ out) {
  int s = blockIdx.x, tid = threadIdx.x;
  int wave = tid >> 6, lane = tid & 63;
  __shared__ float hs[KH], cs[KH], xs[KDW], g[4*KH];
  __shared__ unsigned long long wbest[4];
  __shared__ int widxS;

  if (tid < KH) { hs[tid] = hg[s*KH + tid]; cs[tid] = cg[s*KH + tid]; }
  __syncthreads();

  for (int t = 0; t < KRW; ++t) {
    int r = s*KRW + t;
    int nc = candcnt[r];
    unsigned long long best = 0ull;
    if (nc >= 0) {
      // wave ci%4 handles candidate ci: lanes 0..39 do the 40-term dot in parallel
      for (int ci = wave; ci < nc; ci += 4) {
        int2 cd = candbuf[(size_t)r*CMAX + ci];
        float key = __int_as_float(cd.x);
        int col = cd.y;
        float p = (lane < KH) ? hs[lane] * W_up[lane*KN + col] : 0.f;
#pragma unroll
        for (int d = 32; d > 0; d >>= 1) p += __shfl_xor(p, d, 64);
        unsigned long long pk = packsc_(key + p, col);
        if (pk > best) best = pk;
      }
    } else {
      // exact fallback (never expected): full-row rescan
      const float* urow = gu + ((size_t)t*KNS + s)*KN;
      for (int col = tid; col < KN; col += 256) {
        float sc = gumbel_(urow[col]) + b_up[col];
#pragma unroll
        for (int k = 0; k < KH; ++k) sc = fmaf(hs[k], W_up[k*KN + col], sc);
        unsigned long long pk = packsc_(sc, col);
        if (pk > best) best = pk;
      }
    }
#pragma unroll
    for (int d = 32; d > 0; d >>= 1) {
      unsigned long long q = (unsigned long long)__shfl_xor((long long)best, d, 64);
      if (q > best) best = q;
    }
    if (lane == 0) wbest[wave] = best;
    __syncthreads();                                   // sync: wave bests ready
    if (tid == 0) {
      unsigned long long fb = wbest[0];
      if (wbest[1] > fb) fb = wbest[1];
      if (wbest[2] > fb) fb = wbest[2];
      if (wbest[3] > fb) fb = wbest[3];
      int w = (int)(~(unsigned)(fb & 0xFFFFFFFFull));
      widxS = w;
      out[((size_t)s*KRW + t)*KN + w] = 1.0f;          // spike (zeros laid by stream)
    }
    __syncthreads();                                   // sync: widx published
    if (t < KRW - 1) {
      if (tid < KDW) xs[tid] = W_down[(size_t)widxS*KDW + tid];
      __syncthreads();                                 // sync: xs ready
      if (tid < 4*KH) {
        float a = b_ih[tid] + b_hh[tid];
#pragma unroll 8
        for (int k = 0; k < KDW; ++k) a = fmaf(xs[k], w_ih[k*4*KH + tid], a);
#pragma unroll 8
        for (int k = 0; k < KH; ++k) a = fmaf(hs[k], w_hh[k*4*KH + tid], a);
        g[tid] = a;
      }
      __syncthreads();                                 // sync: gates ready
      if (tid < KH) {
        float gi = g[tid], gf = g[KH+tid], gg2 = g[2*KH+tid], go = g[3*KH+tid];
        float cn = sigmoidf_(gf) * cs[tid] + sigmoidf_(gi) * tanhf(gg2);
        float hn_ = sigmoidf_(go) * tanhf(cn);
        hs[tid] = hn_; cs[tid] = cn;
      }
      __syncthreads();                                 // sync: hs published for next t
    }
  }
}

extern "C" void kernel_launch(void* const* d_in, const int* in_sizes, int n_in,
                              void* d_out, int out_size, void* d_ws, size_t ws_size,
                              hipStream_t stream) {
  const float* z      = (const float*)d_in[0];
  const float* gu     = (const float*)d_in[1];
  const float* l1w    = (const float*)d_in[2];
  const float* l1b    = (const float*)d_in[3];
  const float* l2w    = (const float*)d_in[4];
  const float* l2b    = (const float*)d_in[5];
  const float* l3w    = (const float*)d_in[6];
  const float* l3b    = (const float*)d_in[7];
  const float* w_ih   = (const float*)d_in[8];
  const float* w_hh   = (const float*)d_in[9];
  const float* b_ih   = (const float*)d_in[10];
  const float* b_hh   = (const float*)d_in[11];
  const float* W_up   = (const float*)d_in[12];
  const float* b_up   = (const float*)d_in[13];
  const float* W_down = (const float*)d_in[14];
  float* out = (float*)d_out;

  // workspace (~2.5 MB), every byte rewritten each call
  char* ws = (char*)d_ws;
  size_t off = 0;
  float* h  = (float*)(ws + off); off += (size_t)KNS*KH*4;
  float* c  = (float*)(ws + off); off += (size_t)KNS*KH*4;
  float* pp = (float*)(ws + off); off += (size_t)NROW*KCH*4;
  float* wpart = (float*)(ws + off); off += 128*4;
  int2* candbuf = (int2*)(ws + off); off += (size_t)NROW*CMAX*8;
  int* candcnt = (int*)(ws + off);

  k_init_wnorm<<<KNS + KCH, 256, 0, stream>>>(z, l1w, l1b, l2w, l2b, l3w, l3b,
                                              b_ih, b_hh, w_hh, W_up, h, c, wpart);

  k_score_zero<<<dim3(KNS, KRW), 256, 0, stream>>>(gu, b_up, pp, out);

  k_cands<<<NROW, 128, 0, stream>>>(pp, gu, b_up, wpart, candbuf, candcnt);

  k_final<<<KNS, 256, 0, stream>>>(candbuf, candcnt, gu, W_up, b_up, h, c,
                                   W_down, w_ih, w_hh, b_ih, b_hh, out);
}

// Round 17
// 190.625 us; speedup vs baseline: 1.7617x; 1.0226x over previous
//
#include <hip/hip_runtime.h>
#include <math.h>

// Problem constants (from reference)
#define KN    20000   // vocab
#define KH    40      // LSTM hidden
#define KDW   128     // W_down width
#define KND   16      // noise dim
#define KRW   8       // rw_len
#define KNS   512     // n_sample
#define KCH   79      // chunks of 256 cols per row
#define NROW  (KRW*KNS)
#define CMAX  32      // candidate cap per row (overflow -> exact fallback)
#define KEPS  1e-20f
#define KLN2  0.69314718055994531f
#define HBND  6.32455532f   // sqrt(40): ||h|| bound (h entries are sigmoid*tanh in (-1,1))
#define NINF  (-__builtin_inff())

typedef float floatx4 __attribute__((ext_vector_type(4)));

__device__ __forceinline__ float sigmoidf_(float x) { return 1.0f / (1.0f + expf(-x)); }

// pack (score, col) into a monotone u64 key; larger = better; ties -> smaller col.
__device__ __forceinline__ unsigned long long packsc_(float v, int col) {
  unsigned u = __float_as_uint(v);
  unsigned key = (u >> 31) ? ~u : (u | 0x80000000u);
  return ((unsigned long long)key << 32) | (unsigned)(~col);
}
// Gumbel(0,1) from uniform u — identical op DAG everywhere keys are made.
// Monotone increasing in u (used for bound transport in k_cands).
__device__ __forceinline__ float gumbel_(float u) {
  float t = fmaf(-KLN2, __log2f(u + KEPS), KEPS);   // -ln(u+eps)+eps
  return -KLN2 * __log2f(t);                         // -ln(.)
}

// -------- merged: init MLP+LSTM0 (blocks 0..511) | wnorm+bmax partials (512..590) --------
__global__ void __launch_bounds__(256) k_init_wnorm(
    const float* __restrict__ z,
    const float* __restrict__ l1w, const float* __restrict__ l1b,
    const float* __restrict__ l2w, const float* __restrict__ l2b,
    const float* __restrict__ l3w, const float* __restrict__ l3b,
    const float* __restrict__ b_ih, const float* __restrict__ b_hh,
    const float* __restrict__ w_hh, const float* __restrict__ W_up,
    const float* __restrict__ b_up,
    float* __restrict__ h, float* __restrict__ c,
    float* __restrict__ wpart, float* __restrict__ bpart) {
  int tid = threadIdx.x;
  __shared__ float zs[KND], inter[KH], h0[KH], c0[KH], g[4*KH];
  __shared__ float wm[4], bm[4];
  if (blockIdx.x >= KNS) {
    int b = blockIdx.x - KNS;
    int j = b*256 + tid;
    int lane = tid & 63, grp = tid >> 6;
    float ss = 0.f, ab = 0.f;
    if (j < KN) {
#pragma unroll
      for (int k = 0; k < KH; ++k) { float w = W_up[k*KN + j]; ss = fmaf(w, w, ss); }
      ab = fabsf(b_up[j]);
    }
    float wn = sqrtf(ss);
#pragma unroll
    for (int d = 32; d > 0; d >>= 1) {
      wn = fmaxf(wn, __shfl_xor(wn, d, 64));
      ab = fmaxf(ab, __shfl_xor(ab, d, 64));
    }
    if (lane == 0) { wm[grp] = wn; bm[grp] = ab; }
    __syncthreads();
    if (tid == 0) {
      wpart[b] = fmaxf(fmaxf(wm[0], wm[1]), fmaxf(wm[2], wm[3]));
      bpart[b] = fmaxf(fmaxf(bm[0], bm[1]), fmaxf(bm[2], bm[3]));
    }
    return;
  }
  int s = blockIdx.x;
  if (tid < KND) zs[tid] = z[s*KND + tid];
  __syncthreads();
  if (tid < KH) {
    float a = l1b[tid];
#pragma unroll
    for (int k = 0; k < KND; ++k) a = fmaf(zs[k], l1w[k*KH + tid], a);
    inter[tid] = tanhf(a);
  }
  __syncthreads();
  if (tid < KH) {
    float a2 = l2b[tid], a3 = l3b[tid];
#pragma unroll
    for (int k = 0; k < KH; ++k) {
      float iv = inter[k];
      a2 = fmaf(iv, l2w[k*KH + tid], a2);
      a3 = fmaf(iv, l3w[k*KH + tid], a3);
    }
    h0[tid] = tanhf(a2);
    c0[tid] = tanhf(a3);
  }
  __syncthreads();
  if (tid < 4*KH) {
    float a = b_ih[tid] + b_hh[tid];          // x0 = 0 -> no w_ih term
#pragma unroll 8
    for (int k = 0; k < KH; ++k) a = fmaf(h0[k], w_hh[k*4*KH + tid], a);
    g[tid] = a;
  }
  __syncthreads();
  if (tid < KH) {
    float gi = g[tid], gf = g[KH+tid], gg = g[2*KH+tid], go = g[3*KH+tid];
    float cn = sigmoidf_(gf) * c0[tid] + sigmoidf_(gi) * tanhf(gg);
    float hn = sigmoidf_(go) * tanhf(cn);
    h[s*KH + tid] = hn;
    c[s*KH + tid] = cn;
  }
}

// ------- stream: COMPUTE-FREE. Per (s,t) row: 20 upfront float4 loads,
//         chunk maxima of RAW u (fmax only, no transcendentals) -> pp,
//         NT zero stores last. Gumbel moved to k_cands via monotonicity. -------
__global__ void __launch_bounds__(256) k_score_zero(
    const float* __restrict__ gu,           // [RW][NS][KN]
    float* __restrict__ pp,                 // [NS*RW][KCH]  u-space chunk maxima
    float* __restrict__ out) {              // [NS][RW][KN]
  int s = blockIdx.x, t = blockIdx.y;
  int tid = threadIdx.x, grp = tid >> 6, lane = tid & 63;
  __shared__ float cm[KCH + 1];
  const float* urow = gu + ((size_t)t*KNS + s)*KN;
  float* orow = out + ((size_t)s*KRW + t)*KN;

  floatx4 u4[20];
#pragma unroll
  for (int it = 0; it < 20; ++it) {
    int col = (it*256 + tid) * 4;
    u4[it] = *(const floatx4*)(urow + (col < KN ? col : KN - 4));
  }
  float m[20];
#pragma unroll
  for (int it = 0; it < 20; ++it) {
    int col = (it*256 + tid) * 4;
    bool v = col < KN;
    float mm = fmaxf(fmaxf(u4[it][0], u4[it][1]), fmaxf(u4[it][2], u4[it][3]));
    m[it] = v ? mm : NINF;
  }
#pragma unroll
  for (int d = 32; d > 0; d >>= 1) {
#pragma unroll
    for (int it = 0; it < 20; ++it)
      m[it] = fmaxf(m[it], __shfl_xor(m[it], d, 64));
  }
#pragma unroll
  for (int it = 0; it < 20; ++it) {
    int ch = it*4 + grp;
    if (lane == 0 && ch < KCH) cm[ch] = m[it];
  }
  __syncthreads();
  if (tid < KCH) pp[((size_t)s*KRW + t)*KCH + tid] = cm[tid];

  floatx4 zv = (floatx4)(0.f);
#pragma unroll
  for (int it = 0; it < 20; ++it) {
    int col = (it*256 + tid) * 4;
    if (col < KN) __builtin_nontemporal_store(zv, (floatx4*)(orow + col));
  }
}

// ------- candidate extraction (h-independent threshold, u->key via monotone g):
//   rowmax_key >= g(umax_row) - bmax; thr = that - 2*sqrt(40)*wnmax - margin.
//   Chunk screened iff g(chunk_umax) + bmax >= thr - margin. Exact keys on
//   candidate chunks' columns; emit (key,col) (cap CMAX, overflow -> -1). -------
__global__ void __launch_bounds__(128) k_cands(
    const float* __restrict__ pp,           // [NROW][KCH] u-space
    const float* __restrict__ gu,
    const float* __restrict__ b_up,
    const float* __restrict__ wpart,        // [KCH]
    const float* __restrict__ bpart,        // [KCH]
    int2* __restrict__ candbuf,             // [NROW][CMAX]  (.x=key bits, .y=col)
    int* __restrict__ candcnt) {            // [NROW]
  int r = blockIdx.x;                       // r = s*KRW + t
  int s = r / KRW, t = r - s*KRW;
  int tid = threadIdx.x, lane = tid & 63, wave = tid >> 6;
  __shared__ float sThr, sBm;
  __shared__ int chlist[KCH], nch, ncand, ovf;
  if (tid == 0) { nch = 0; ncand = 0; ovf = 0; }
  __syncthreads();

  if (wave == 0) {
    float ua = pp[(size_t)r*KCH + lane];                   // lane<64<79 valid
    float ub = (lane + 64 < KCH) ? pp[(size_t)r*KCH + lane + 64] : NINF;
    float um = fmaxf(ua, ub);
    float wa = (lane < KCH) ? wpart[lane] : NINF;
    float wb = (lane + 64 < KCH) ? wpart[lane + 64] : NINF;
    float wm = fmaxf(wa, wb);
    float ba = (lane < KCH) ? bpart[lane] : NINF;
    float bb = (lane + 64 < KCH) ? bpart[lane + 64] : NINF;
    float bmx = fmaxf(ba, bb);
#pragma unroll
    for (int d = 32; d > 0; d >>= 1) {
      um  = fmaxf(um,  __shfl_xor(um,  d, 64));
      wm  = fmaxf(wm,  __shfl_xor(wm,  d, 64));
      bmx = fmaxf(bmx, __shfl_xor(bmx, d, 64));
    }
    if (lane == 0) {
      float lb = gumbel_(um) - bmx;                        // rowmax_key lower bound
      sThr = lb - (2.0f * HBND * wm * 1.001f + 1e-3f) - 2e-3f;
      sBm  = bmx;
    }
  }
  __syncthreads();
  float thr = sThr, bmx = sBm;
  // chunk screen: upper bound of any key in chunk = g(chunk_umax) + bmax (+wiggle)
  if (tid < KCH && gumbel_(pp[(size_t)r*KCH + tid]) + bmx + 2e-3f >= thr) {
    int i = atomicAdd(&nch, 1);
    chlist[i] = tid;
  }
  __syncthreads();
  int nchunks = nch;
  const float* urow = gu + ((size_t)t*KNS + s)*KN;
  for (int ci = 0; ci < nchunks; ++ci) {
    int base = chlist[ci]*256;
#pragma unroll
    for (int half = 0; half < 2; ++half) {
      int col = base + half*128 + tid;
      if (col < KN) {
        float key = gumbel_(urow[col]) + b_up[col];        // exact key
        if (key >= thr) {
          int i = atomicAdd(&ncand, 1);
          if (i < CMAX) candbuf[(size_t)r*CMAX + i] = make_int2(__float_as_int(key), col);
          else ovf = 1;
        }
      }
    }
  }
  __syncthreads();
  if (tid == 0) candcnt[r] = ovf ? -1 : ncand;
}

// ------- final: block = sample; 8 steps of {best candidate via wave-parallel
//         dot, spike write, LSTM advance}. -------
__global__ void __launch_bounds__(256) k_final(
    const int2* __restrict__ candbuf, const int* __restrict__ candcnt,
    const float* __restrict__ gu,
    const float* __restrict__ W_up, const float* __restrict__ b_up,
    const float* __restrict__ hg, const float* __restrict__ cg,
    const float* __restrict__ W_down,
    const float* __restrict__ w_ih, const float* __restrict__ w_hh,
    const float* __restrict__ b_ih, const float* __restrict__ b_hh,
    float* __restrict__ out) {
  int s = blockIdx.x, tid = threadIdx.x;
  int wave = tid >> 6, lane = tid & 63;
  __shared__ float hs[KH], cs[KH], xs[KDW], g[4*KH];
  __shared__ unsigned long long wbest[4];
  __shared__ int widxS;

  if (tid < KH) { hs[tid] = hg[s*KH + tid]; cs[tid] = cg[s*KH + tid]; }
  __syncthreads();

  for (int t = 0; t < KRW; ++t) {
    int r = s*KRW + t;
    int nc = candcnt[r];
    unsigned long long best = 0ull;
    if (nc >= 0) {
      for (int ci = wave; ci < nc; ci += 4) {
        int2 cd = candbuf[(size_t)r*CMAX + ci];
        float key = __int_as_float(cd.x);
        int col = cd.y;
        float p = (lane < KH) ? hs[lane] * W_up[lane*KN + col] : 0.f;
#pragma unroll
        for (int d = 32; d > 0; d >>= 1) p += __shfl_xor(p, d, 64);
        unsigned long long pk = packsc_(key + p, col);
        if (pk > best) best = pk;
      }
    } else {
      // exact fallback (never expected): full-row rescan
      const float* urow = gu + ((size_t)t*KNS + s)*KN;
      for (int col = tid; col < KN; col += 256) {
        float sc = gumbel_(urow[col]) + b_up[col];
#pragma unroll
        for (int k = 0; k < KH; ++k) sc = fmaf(hs[k], W_up[k*KN + col], sc);
        unsigned long long pk = packsc_(sc, col);
        if (pk > best) best = pk;
      }
    }
#pragma unroll
    for (int d = 32; d > 0; d >>= 1) {
      unsigned long long q = (unsigned long long)__shfl_xor((long long)best, d, 64);
      if (q > best) best = q;
    }
    if (lane == 0) wbest[wave] = best;
    __syncthreads();
    if (tid == 0) {
      unsigned long long fb = wbest[0];
      if (wbest[1] > fb) fb = wbest[1];
      if (wbest[2] > fb) fb = wbest[2];
      if (wbest[3] > fb) fb = wbest[3];
      int w = (int)(~(unsigned)(fb & 0xFFFFFFFFull));
      widxS = w;
      out[((size_t)s*KRW + t)*KN + w] = 1.0f;          // spike (zeros laid by stream)
    }
    __syncthreads();
    if (t < KRW - 1) {
      if (tid < KDW) xs[tid] = W_down[(size_t)widxS*KDW + tid];
      __syncthreads();
      if (tid < 4*KH) {
        float a = b_ih[tid] + b_hh[tid];
#pragma unroll 8
        for (int k = 0; k < KDW; ++k) a = fmaf(xs[k], w_ih[k*4*KH + tid], a);
#pragma unroll 8
        for (int k = 0; k < KH; ++k) a = fmaf(hs[k], w_hh[k*4*KH + tid], a);
        g[tid] = a;
      }
      __syncthreads();
      if (tid < KH) {
        float gi = g[tid], gf = g[KH+tid], gg2 = g[2*KH+tid], go = g[3*KH+tid];
        float cn = sigmoidf_(gf) * cs[tid] + sigmoidf_(gi) * tanhf(gg2);
        float hn_ = sigmoidf_(go) * tanhf(cn);
        hs[tid] = hn_; cs[tid] = cn;
      }
      __syncthreads();
    }
  }
}

extern "C" void kernel_launch(void* const* d_in, const int* in_sizes, int n_in,
                              void* d_out, int out_size, void* d_ws, size_t ws_size,
                              hipStream_t stream) {
  const float* z      = (const float*)d_in[0];
  const float* gu     = (const float*)d_in[1];
  const float* l1w    = (const float*)d_in[2];
  const float* l1b    = (const float*)d_in[3];
  const float* l2w    = (const float*)d_in[4];
  const float* l2b    = (const float*)d_in[5];
  const float* l3w    = (const float*)d_in[6];
  const float* l3b    = (const float*)d_in[7];
  const float* w_ih   = (const float*)d_in[8];
  const float* w_hh   = (const float*)d_in[9];
  const float* b_ih   = (const float*)d_in[10];
  const float* b_hh   = (const float*)d_in[11];
  const float* W_up   = (const float*)d_in[12];
  const float* b_up   = (const float*)d_in[13];
  const float* W_down = (const float*)d_in[14];
  float* out = (float*)d_out;

  // workspace (~2.5 MB), every byte rewritten each call
  char* ws = (char*)d_ws;
  size_t off = 0;
  float* h  = (float*)(ws + off); off += (size_t)KNS*KH*4;
  float* c  = (float*)(ws + off); off += (size_t)KNS*KH*4;
  float* pp = (float*)(ws + off); off += (size_t)NROW*KCH*4;
  float* wpart = (float*)(ws + off); off += 128*4;
  float* bpart = (float*)(ws + off); off += 128*4;
  int2* candbuf = (int2*)(ws + off); off += (size_t)NROW*CMAX*8;
  int* candcnt = (int*)(ws + off);

  k_init_wnorm<<<KNS + KCH, 256, 0, stream>>>(z, l1w, l1b, l2w, l2b, l3w, l3b,
                                              b_ih, b_hh, w_hh, W_up, b_up,
                                              h, c, wpart, bpart);

  k_score_zero<<<dim3(KNS, KRW), 256, 0, stream>>>(gu, pp, out);

  k_cands<<<NROW, 128, 0, stream>>>(pp, gu, b_up, wpart, bpart, candbuf, candcnt);

  k_final<<<KNS, 256, 0, stream>>>(candbuf, candcnt, gu, W_up, b_up, h, c,
                                   W_down, w_ih, w_hh, b_ih, b_hh, out);
}

// Round 18
// 187.496 us; speedup vs baseline: 1.7911x; 1.0167x over previous
//
#include <hip/hip_runtime.h>
#include <math.h>

// Problem constants (from reference)
#define KN    20000   // vocab
#define KH    40      // LSTM hidden
#define KDW   128     // W_down width
#define KND   16      // noise dim
#define KRW   8       // rw_len
#define KNS   512     // n_sample
#define KCH   79      // chunks of 256 cols per row
#define NROW  (KRW*KNS)
#define CMAX  32      // candidate cap per row (overflow -> exact fallback)
#define KEPS  1e-20f
#define KLN2  0.69314718055994531f
#define HBND  6.32455532f   // sqrt(40): ||h|| bound (h entries are sigmoid*tanh in (-1,1))
#define NINF  (-__builtin_inff())

typedef float floatx4 __attribute__((ext_vector_type(4)));
#define AS1 __attribute__((address_space(1)))
#define AS3 __attribute__((address_space(3)))

__device__ __forceinline__ float sigmoidf_(float x) { return 1.0f / (1.0f + expf(-x)); }

// pack (score, col) into a monotone u64 key; larger = better; ties -> smaller col.
__device__ __forceinline__ unsigned long long packsc_(float v, int col) {
  unsigned u = __float_as_uint(v);
  unsigned key = (u >> 31) ? ~u : (u | 0x80000000u);
  return ((unsigned long long)key << 32) | (unsigned)(~col);
}
// Gumbel(0,1) from uniform u — identical op DAG everywhere keys are made.
__device__ __forceinline__ float gumbel_(float u) {
  float t = fmaf(-KLN2, __log2f(u + KEPS), KEPS);   // -ln(u+eps)+eps
  return -KLN2 * __log2f(t);                         // -ln(.)
}

// -------- merged: init MLP+LSTM0 (blocks 0..511) | wnorm+bmax partials (512..590) --------
__global__ void __launch_bounds__(256) k_init_wnorm(
    const float* __restrict__ z,
    const float* __restrict__ l1w, const float* __restrict__ l1b,
    const float* __restrict__ l2w, const float* __restrict__ l2b,
    const float* __restrict__ l3w, const float* __restrict__ l3b,
    const float* __restrict__ b_ih, const float* __restrict__ b_hh,
    const float* __restrict__ w_hh, const float* __restrict__ W_up,
    const float* __restrict__ b_up,
    float* __restrict__ h, float* __restrict__ c,
    float* __restrict__ wpart, float* __restrict__ bpart) {
  int tid = threadIdx.x;
  __shared__ float zs[KND], inter[KH], h0[KH], c0[KH], g[4*KH];
  __shared__ float wm[4], bm[4];
  if (blockIdx.x >= KNS) {
    int b = blockIdx.x - KNS;
    int j = b*256 + tid;
    int lane = tid & 63, grp = tid >> 6;
    float ss = 0.f, ab = 0.f;
    if (j < KN) {
#pragma unroll
      for (int k = 0; k < KH; ++k) { float w = W_up[k*KN + j]; ss = fmaf(w, w, ss); }
      ab = fabsf(b_up[j]);
    }
    float wn = sqrtf(ss);
#pragma unroll
    for (int d = 32; d > 0; d >>= 1) {
      wn = fmaxf(wn, __shfl_xor(wn, d, 64));
      ab = fmaxf(ab, __shfl_xor(ab, d, 64));
    }
    if (lane == 0) { wm[grp] = wn; bm[grp] = ab; }
    __syncthreads();
    if (tid == 0) {
      wpart[b] = fmaxf(fmaxf(wm[0], wm[1]), fmaxf(wm[2], wm[3]));
      bpart[b] = fmaxf(fmaxf(bm[0], bm[1]), fmaxf(bm[2], bm[3]));
    }
    return;
  }
  int s = blockIdx.x;
  if (tid < KND) zs[tid] = z[s*KND + tid];
  __syncthreads();
  if (tid < KH) {
    float a = l1b[tid];
#pragma unroll
    for (int k = 0; k < KND; ++k) a = fmaf(zs[k], l1w[k*KH + tid], a);
    inter[tid] = tanhf(a);
  }
  __syncthreads();
  if (tid < KH) {
    float a2 = l2b[tid], a3 = l3b[tid];
#pragma unroll
    for (int k = 0; k < KH; ++k) {
      float iv = inter[k];
      a2 = fmaf(iv, l2w[k*KH + tid], a2);
      a3 = fmaf(iv, l3w[k*KH + tid], a3);
    }
    h0[tid] = tanhf(a2);
    c0[tid] = tanhf(a3);
  }
  __syncthreads();
  if (tid < 4*KH) {
    float a = b_ih[tid] + b_hh[tid];          // x0 = 0 -> no w_ih term
#pragma unroll 8
    for (int k = 0; k < KH; ++k) a = fmaf(h0[k], w_hh[k*4*KH + tid], a);
    g[tid] = a;
  }
  __syncthreads();
  if (tid < KH) {
    float gi = g[tid], gf = g[KH+tid], gg = g[2*KH+tid], go = g[3*KH+tid];
    float cn = sigmoidf_(gf) * c0[tid] + sigmoidf_(gi) * tanhf(gg);
    float hn = sigmoidf_(go) * tanhf(cn);
    h[s*KH + tid] = hn;
    c[s*KH + tid] = cn;
  }
}

// ------- stream via global_load_lds: block = one (s,t) row, 1024 thr, 80KB LDS.
//   (1) NT zero stores issued first (write stream in flight),
//   (2) 5x global_load_lds(16B)/thread, linear LDS = linear global,
//   (3) barrier drains both, (4) chunk maxima from LDS (wave = 1 chunk/iter),
//   (5) pp store. -------
__global__ void __launch_bounds__(1024) k_score_zero(
    const float* __restrict__ gu,           // [RW][NS][KN]
    float* __restrict__ pp,                 // [NS*RW][KCH]  u-space chunk maxima
    float* __restrict__ out) {              // [NS][RW][KN]
  int s = blockIdx.x, t = blockIdx.y;
  int tid = threadIdx.x, wave = tid >> 6, lane = tid & 63;
  extern __shared__ float smem[];           // [20000] row + [80] cm
  float* lds = smem;
  float* cm  = smem + KN;
  const float* urow = gu + ((size_t)t*KNS + s)*KN;
  float* orow = out + ((size_t)s*KRW + t)*KN;

  // (1) write stream first: 5 NT zero float4 stores per thread
  floatx4 zv = (floatx4)(0.f);
#pragma unroll
  for (int k = 0; k < 5; ++k) {
    int i = k*1024 + tid;                   // float4 index, 5000 per row
    if (i < 5000) __builtin_nontemporal_store(zv, (floatx4*)orow + i);
  }

  // (2) read stream: direct-to-LDS, wave-uniform base + lane*16
#pragma unroll
  for (int k = 0; k < 5; ++k) {
    int i = k*1024 + tid;                   // this thread's float4 index
    if (i < 5000) {
      const AS1 unsigned* gsrc =
          (const AS1 unsigned*)(urow + (size_t)i*4);
      AS3 unsigned* ldst =
          (AS3 unsigned*)(lds + (size_t)(k*1024 + wave*64)*4);  // wave-uniform
      __builtin_amdgcn_global_load_lds(gsrc, ldst, 16, 0, 0);
    }
  }
  __syncthreads();                          // drains vmcnt (loads+stores) + barrier

  // (4) chunk maxima from LDS: wave handles chunk (k*16+wave) each iteration
  float m[5];
#pragma unroll
  for (int k = 0; k < 5; ++k) {
    int i = k*1024 + tid;
    bool v = i < 5000;
    floatx4 u4;
    if (v) u4 = *(const floatx4*)(lds + (size_t)i*4);
    else   u4 = (floatx4)(0.f);
    float mm = fmaxf(fmaxf(u4[0], u4[1]), fmaxf(u4[2], u4[3]));
    m[k] = v ? mm : NINF;
  }
#pragma unroll
  for (int d = 32; d > 0; d >>= 1) {
#pragma unroll
    for (int k = 0; k < 5; ++k)
      m[k] = fmaxf(m[k], __shfl_xor(m[k], d, 64));
  }
  if (lane == 0) {
#pragma unroll
    for (int k = 0; k < 5; ++k) {
      int ch = k*16 + wave;
      if (ch < KCH) cm[ch] = m[k];
    }
  }
  __syncthreads();
  if (tid < KCH) pp[((size_t)s*KRW + t)*KCH + tid] = cm[tid];
}

// ------- candidate extraction (h-independent threshold, u->key via monotone g) -------
__global__ void __launch_bounds__(128) k_cands(
    const float* __restrict__ pp,           // [NROW][KCH] u-space
    const float* __restrict__ gu,
    const float* __restrict__ b_up,
    const float* __restrict__ wpart,        // [KCH]
    const float* __restrict__ bpart,        // [KCH]
    int2* __restrict__ candbuf,             // [NROW][CMAX]  (.x=key bits, .y=col)
    int* __restrict__ candcnt) {            // [NROW]
  int r = blockIdx.x;                       // r = s*KRW + t
  int s = r / KRW, t = r - s*KRW;
  int tid = threadIdx.x, lane = tid & 63, wave = tid >> 6;
  __shared__ float sThr, sBm;
  __shared__ int chlist[KCH], nch, ncand, ovf;
  if (tid == 0) { nch = 0; ncand = 0; ovf = 0; }
  __syncthreads();

  if (wave == 0) {
    float ua = pp[(size_t)r*KCH + lane];                   // lane<64<79 valid
    float ub = (lane + 64 < KCH) ? pp[(size_t)r*KCH + lane + 64] : NINF;
    float um = fmaxf(ua, ub);
    float wa = (lane < KCH) ? wpart[lane] : NINF;
    float wb = (lane + 64 < KCH) ? wpart[lane + 64] : NINF;
    float wm = fmaxf(wa, wb);
    float ba = (lane < KCH) ? bpart[lane] : NINF;
    float bb = (lane + 64 < KCH) ? bpart[lane + 64] : NINF;
    float bmx = fmaxf(ba, bb);
#pragma unroll
    for (int d = 32; d > 0; d >>= 1) {
      um  = fmaxf(um,  __shfl_xor(um,  d, 64));
      wm  = fmaxf(wm,  __shfl_xor(wm,  d, 64));
      bmx = fmaxf(bmx, __shfl_xor(bmx, d, 64));
    }
    if (lane == 0) {
      float lb = gumbel_(um) - bmx;                        // rowmax_key lower bound
      sThr = lb - (2.0f * HBND * wm * 1.001f + 1e-3f) - 2e-3f;
      sBm  = bmx;
    }
  }
  __syncthreads();
  float thr = sThr, bmx = sBm;
  if (tid < KCH && gumbel_(pp[(size_t)r*KCH + tid]) + bmx + 2e-3f >= thr) {
    int i = atomicAdd(&nch, 1);
    chlist[i] = tid;
  }
  __syncthreads();
  int nchunks = nch;
  const float* urow = gu + ((size_t)t*KNS + s)*KN;
  for (int ci = 0; ci < nchunks; ++ci) {
    int base = chlist[ci]*256;
#pragma unroll
    for (int half = 0; half < 2; ++half) {
      int col = base + half*128 + tid;
      if (col < KN) {
        float key = gumbel_(urow[col]) + b_up[col];        // exact key
        if (key >= thr) {
          int i = atomicAdd(&ncand, 1);
          if (i < CMAX) candbuf[(size_t)r*CMAX + i] = make_int2(__float_as_int(key), col);
          else ovf = 1;
        }
      }
    }
  }
  __syncthreads();
  if (tid == 0) candcnt[r] = ovf ? -1 : ncand;
}

// ------- final: block = sample; 8 steps of {best candidate via wave-parallel
//         dot, spike write, LSTM advance}. -------
__global__ void __launch_bounds__(256) k_final(
    const int2* __restrict__ candbuf, const int* __restrict__ candcnt,
    const float* __restrict__ gu,
    const float* __restrict__ W_up, const float* __restrict__ b_up,
    const float* __restrict__ hg, const float* __restrict__ cg,
    const float* __restrict__ W_down,
    const float* __restrict__ w_ih, const float* __restrict__ w_hh,
    const float* __restrict__ b_ih, const float* __restrict__ b_hh,
    float* __restrict__ out) {
  int s = blockIdx.x, tid = threadIdx.x;
  int wave = tid >> 6, lane = tid & 63;
  __shared__ float hs[KH], cs[KH], xs[KDW], g[4*KH];
  __shared__ unsigned long long wbest[4];
  __shared__ int widxS;

  if (tid < KH) { hs[tid] = hg[s*KH + tid]; cs[tid] = cg[s*KH + tid]; }
  __syncthreads();

  for (int t = 0; t < KRW; ++t) {
    int r = s*KRW + t;
    int nc = candcnt[r];
    unsigned long long best = 0ull;
    if (nc >= 0) {
      for (int ci = wave; ci < nc; ci += 4) {
        int2 cd = candbuf[(size_t)r*CMAX + ci];
        float key = __int_as_float(cd.x);
        int col = cd.y;
        float p = (lane < KH) ? hs[lane] * W_up[lane*KN + col] : 0.f;
#pragma unroll
        for (int d = 32; d > 0; d >>= 1) p += __shfl_xor(p, d, 64);
        unsigned long long pk = packsc_(key + p, col);
        if (pk > best) best = pk;
      }
    } else {
      // exact fallback (never expected): full-row rescan
      const float* urow = gu + ((size_t)t*KNS + s)*KN;
      for (int col = tid; col < KN; col += 256) {
        float sc = gumbel_(urow[col]) + b_up[col];
#pragma unroll
        for (int k = 0; k < KH; ++k) sc = fmaf(hs[k], W_up[k*KN + col], sc);
        unsigned long long pk = packsc_(sc, col);
        if (pk > best) best = pk;
      }
    }
#pragma unroll
    for (int d = 32; d > 0; d >>= 1) {
      unsigned long long q = (unsigned long long)__shfl_xor((long long)best, d, 64);
      if (q > best) best = q;
    }
    if (lane == 0) wbest[wave] = best;
    __syncthreads();
    if (tid == 0) {
      unsigned long long fb = wbest[0];
      if (wbest[1] > fb) fb = wbest[1];
      if (wbest[2] > fb) fb = wbest[2];
      if (wbest[3] > fb) fb = wbest[3];
      int w = (int)(~(unsigned)(fb & 0xFFFFFFFFull));
      widxS = w;
      out[((size_t)s*KRW + t)*KN + w] = 1.0f;          // spike (zeros laid by stream)
    }
    __syncthreads();
    if (t < KRW - 1) {
      if (tid < KDW) xs[tid] = W_down[(size_t)widxS*KDW + tid];
      __syncthreads();
      if (tid < 4*KH) {
        float a = b_ih[tid] + b_hh[tid];
#pragma unroll 8
        for (int k = 0; k < KDW; ++k) a = fmaf(xs[k], w_ih[k*4*KH + tid], a);
#pragma unroll 8
        for (int k = 0; k < KH; ++k) a = fmaf(hs[k], w_hh[k*4*KH + tid], a);
        g[tid] = a;
      }
      __syncthreads();
      if (tid < KH) {
        float gi = g[tid], gf = g[KH+tid], gg2 = g[2*KH+tid], go = g[3*KH+tid];
        float cn = sigmoidf_(gf) * cs[tid] + sigmoidf_(gi) * tanhf(gg2);
        float hn_ = sigmoidf_(go) * tanhf(cn);
        hs[tid] = hn_; cs[tid] = cn;
      }
      __syncthreads();
    }
  }
}

extern "C" void kernel_launch(void* const* d_in, const int* in_sizes, int n_in,
                              void* d_out, int out_size, void* d_ws, size_t ws_size,
                              hipStream_t stream) {
  const float* z      = (const float*)d_in[0];
  const float* gu     = (const float*)d_in[1];
  const float* l1w    = (const float*)d_in[2];
  const float* l1b    = (const float*)d_in[3];
  const float* l2w    = (const float*)d_in[4];
  const float* l2b    = (const float*)d_in[5];
  const float* l3w    = (const float*)d_in[6];
  const float* l3b    = (const float*)d_in[7];
  const float* w_ih   = (const float*)d_in[8];
  const float* w_hh   = (const float*)d_in[9];
  const float* b_ih   = (const float*)d_in[10];
  const float* b_hh   = (const float*)d_in[11];
  const float* W_up   = (const float*)d_in[12];
  const float* b_up   = (const float*)d_in[13];
  const float* W_down = (const float*)d_in[14];
  float* out = (float*)d_out;

  // workspace (~2.5 MB), every byte rewritten each call
  char* ws = (char*)d_ws;
  size_t off = 0;
  float* h  = (float*)(ws + off); off += (size_t)KNS*KH*4;
  float* c  = (float*)(ws + off); off += (size_t)KNS*KH*4;
  float* pp = (float*)(ws + off); off += (size_t)NROW*KCH*4;
  float* wpart = (float*)(ws + off); off += 128*4;
  float* bpart = (float*)(ws + off); off += 128*4;
  int2* candbuf = (int2*)(ws + off); off += (size_t)NROW*CMAX*8;
  int* candcnt = (int*)(ws + off);

  k_init_wnorm<<<KNS + KCH, 256, 0, stream>>>(z, l1w, l1b, l2w, l2b, l3w, l3b,
                                              b_ih, b_hh, w_hh, W_up, b_up,
                                              h, c, wpart, bpart);

  k_score_zero<<<dim3(KNS, KRW), 1024, (size_t)(KN + 128)*4, stream>>>(gu, pp, out);

  k_cands<<<NROW, 128, 0, stream>>>(pp, gu, b_up, wpart, bpart, candbuf, candcnt);

  k_final<<<KNS, 256, 0, stream>>>(candbuf, candcnt, gu, W_up, b_up, h, c,
                                   W_down, w_ih, w_hh, b_ih, b_hh, out);
}

// Round 19
// 184.515 us; speedup vs baseline: 1.8200x; 1.0162x over previous
//
#include <hip/hip_runtime.h>
#include <math.h>

// Problem constants (from reference)
#define KN    20000   // vocab
#define KH    40      // LSTM hidden
#define KDW   128     // W_down width
#define KND   16      // noise dim
#define KRW   8       // rw_len
#define KNS   512     // n_sample
#define KCH   79      // chunks of 256 cols per row
#define NROW  (KRW*KNS)
#define CMAX  32      // candidate cap per row (overflow -> exact fallback)
#define KEPS  1e-20f
#define KLN2  0.69314718055994531f
#define HBND  6.32455532f   // sqrt(40): ||h|| bound (h entries are sigmoid*tanh in (-1,1))
#define NINF  (-__builtin_inff())

typedef float floatx4 __attribute__((ext_vector_type(4)));
#define AS1 __attribute__((address_space(1)))
#define AS3 __attribute__((address_space(3)))

__device__ __forceinline__ float sigmoidf_(float x) { return 1.0f / (1.0f + expf(-x)); }

// pack (score, col) into a monotone u64 key; larger = better; ties -> smaller col.
__device__ __forceinline__ unsigned long long packsc_(float v, int col) {
  unsigned u = __float_as_uint(v);
  unsigned key = (u >> 31) ? ~u : (u | 0x80000000u);
  return ((unsigned long long)key << 32) | (unsigned)(~col);
}
// Gumbel(0,1) from uniform u — identical op DAG everywhere keys are made.
__device__ __forceinline__ float gumbel_(float u) {
  float t = fmaf(-KLN2, __log2f(u + KEPS), KEPS);   // -ln(u+eps)+eps
  return -KLN2 * __log2f(t);                         // -ln(.)
}
// streaming store: bypass L2/L3 allocation (sc0 sc1 nt) — keeps the read path
// free of dirty-line evictions. MALL is memory-side, so coherence is automatic.
__device__ __forceinline__ void store_zero16_stream_(float* p) {
  floatx4 zv = (floatx4)(0.f);
  asm volatile("global_store_dwordx4 %0, %1, off sc0 sc1 nt"
               :: "v"(p), "v"(zv) : "memory");
}

// -------- merged: init MLP+LSTM0 (blocks 0..511) | wnorm+bmax partials (512..590) --------
__global__ void __launch_bounds__(256) k_init_wnorm(
    const float* __restrict__ z,
    const float* __restrict__ l1w, const float* __restrict__ l1b,
    const float* __restrict__ l2w, const float* __restrict__ l2b,
    const float* __restrict__ l3w, const float* __restrict__ l3b,
    const float* __restrict__ b_ih, const float* __restrict__ b_hh,
    const float* __restrict__ w_hh, const float* __restrict__ W_up,
    const float* __restrict__ b_up,
    float* __restrict__ h, float* __restrict__ c,
    float* __restrict__ wpart, float* __restrict__ bpart) {
  int tid = threadIdx.x;
  __shared__ float zs[KND], inter[KH], h0[KH], c0[KH], g[4*KH];
  __shared__ float wm[4], bm[4];
  if (blockIdx.x >= KNS) {
    int b = blockIdx.x - KNS;
    int j = b*256 + tid;
    int lane = tid & 63, grp = tid >> 6;
    float ss = 0.f, ab = 0.f;
    if (j < KN) {
#pragma unroll
      for (int k = 0; k < KH; ++k) { float w = W_up[k*KN + j]; ss = fmaf(w, w, ss); }
      ab = fabsf(b_up[j]);
    }
    float wn = sqrtf(ss);
#pragma unroll
    for (int d = 32; d > 0; d >>= 1) {
      wn = fmaxf(wn, __shfl_xor(wn, d, 64));
      ab = fmaxf(ab, __shfl_xor(ab, d, 64));
    }
    if (lane == 0) { wm[grp] = wn; bm[grp] = ab; }
    __syncthreads();
    if (tid == 0) {
      wpart[b] = fmaxf(fmaxf(wm[0], wm[1]), fmaxf(wm[2], wm[3]));
      bpart[b] = fmaxf(fmaxf(bm[0], bm[1]), fmaxf(bm[2], bm[3]));
    }
    return;
  }
  int s = blockIdx.x;
  if (tid < KND) zs[tid] = z[s*KND + tid];
  __syncthreads();
  if (tid < KH) {
    float a = l1b[tid];
#pragma unroll
    for (int k = 0; k < KND; ++k) a = fmaf(zs[k], l1w[k*KH + tid], a);
    inter[tid] = tanhf(a);
  }
  __syncthreads();
  if (tid < KH) {
    float a2 = l2b[tid], a3 = l3b[tid];
#pragma unroll
    for (int k = 0; k < KH; ++k) {
      float iv = inter[k];
      a2 = fmaf(iv, l2w[k*KH + tid], a2);
      a3 = fmaf(iv, l3w[k*KH + tid], a3);
    }
    h0[tid] = tanhf(a2);
    c0[tid] = tanhf(a3);
  }
  __syncthreads();
  if (tid < 4*KH) {
    float a = b_ih[tid] + b_hh[tid];          // x0 = 0 -> no w_ih term
#pragma unroll 8
    for (int k = 0; k < KH; ++k) a = fmaf(h0[k], w_hh[k*4*KH + tid], a);
    g[tid] = a;
  }
  __syncthreads();
  if (tid < KH) {
    float gi = g[tid], gf = g[KH+tid], gg = g[2*KH+tid], go = g[3*KH+tid];
    float cn = sigmoidf_(gf) * c0[tid] + sigmoidf_(gi) * tanhf(gg);
    float hn = sigmoidf_(go) * tanhf(cn);
    h[s*KH + tid] = hn;
    c[s*KH + tid] = cn;
  }
}

// ------- stream: 1D grid 4096, bijective XCD swizzle (XCD x -> t=x, all s:
//         each XCD streams one contiguous 41MB gu slab). 1024 thr, 80KB LDS.
//   (1) sc0sc1nt zero stores (no L2/L3 allocation -> read path unpolluted),
//   (2) 5x global_load_lds(16B)/thread, (3) barrier, (4) chunk maxima, (5) pp. -------
__global__ void __launch_bounds__(1024) k_score_zero(
    const float* __restrict__ gu,           // [RW][NS][KN]
    float* __restrict__ pp,                 // [NS*RW][KCH]  u-space chunk maxima
    float* __restrict__ out) {              // [NS][RW][KN]
  int bid = blockIdx.x;                     // 0..4095
  int swz = (bid & 7)*512 + (bid >> 3);     // bijective: XCD x gets swz 512x..512x+511
  int t = swz / KNS, s = swz - t*KNS;       // swz = t*KNS + s (contiguous gu rows/XCD)
  int tid = threadIdx.x, wave = tid >> 6, lane = tid & 63;
  extern __shared__ float smem[];           // [20000] row + [80] cm
  float* lds = smem;
  float* cm  = smem + KN;
  const float* urow = gu + (size_t)swz*KN;
  float* orow = out + ((size_t)s*KRW + t)*KN;

  // (1) write stream: streaming stores, no cache allocation
#pragma unroll
  for (int k = 0; k < 5; ++k) {
    int i = k*1024 + tid;                   // float4 index, 5000 per row
    if (i < 5000) store_zero16_stream_((float*)((floatx4*)orow + i));
  }

  // (2) read stream: direct-to-LDS, wave-uniform base + lane*16
#pragma unroll
  for (int k = 0; k < 5; ++k) {
    int i = k*1024 + tid;
    if (i < 5000) {
      const AS1 unsigned* gsrc = (const AS1 unsigned*)(urow + (size_t)i*4);
      AS3 unsigned* ldst = (AS3 unsigned*)(lds + (size_t)(k*1024 + wave*64)*4);
      __builtin_amdgcn_global_load_lds(gsrc, ldst, 16, 0, 0);
    }
  }
  __syncthreads();                          // drains vmcnt (loads+stores) + barrier

  // (4) chunk maxima from LDS
  float m[5];
#pragma unroll
  for (int k = 0; k < 5; ++k) {
    int i = k*1024 + tid;
    bool v = i < 5000;
    floatx4 u4;
    if (v) u4 = *(const floatx4*)(lds + (size_t)i*4);
    else   u4 = (floatx4)(0.f);
    float mm = fmaxf(fmaxf(u4[0], u4[1]), fmaxf(u4[2], u4[3]));
    m[k] = v ? mm : NINF;
  }
#pragma unroll
  for (int d = 32; d > 0; d >>= 1) {
#pragma unroll
    for (int k = 0; k < 5; ++k)
      m[k] = fmaxf(m[k], __shfl_xor(m[k], d, 64));
  }
  if (lane == 0) {
#pragma unroll
    for (int k = 0; k < 5; ++k) {
      int ch = k*16 + wave;
      if (ch < KCH) cm[ch] = m[k];
    }
  }
  __syncthreads();
  if (tid < KCH) pp[((size_t)s*KRW + t)*KCH + tid] = cm[tid];
}

// ------- candidate extraction (h-independent threshold, u->key via monotone g) -------
__global__ void __launch_bounds__(128) k_cands(
    const float* __restrict__ pp,           // [NROW][KCH] u-space
    const float* __restrict__ gu,
    const float* __restrict__ b_up,
    const float* __restrict__ wpart,        // [KCH]
    const float* __restrict__ bpart,        // [KCH]
    int2* __restrict__ candbuf,             // [NROW][CMAX]  (.x=key bits, .y=col)
    int* __restrict__ candcnt) {            // [NROW]
  int r = blockIdx.x;                       // r = s*KRW + t
  int s = r / KRW, t = r - s*KRW;
  int tid = threadIdx.x, lane = tid & 63, wave = tid >> 6;
  __shared__ float sThr, sBm;
  __shared__ int chlist[KCH], nch, ncand, ovf;
  if (tid == 0) { nch = 0; ncand = 0; ovf = 0; }
  __syncthreads();

  if (wave == 0) {
    float ua = pp[(size_t)r*KCH + lane];                   // lane<64<79 valid
    float ub = (lane + 64 < KCH) ? pp[(size_t)r*KCH + lane + 64] : NINF;
    float um = fmaxf(ua, ub);
    float wa = (lane < KCH) ? wpart[lane] : NINF;
    float wb = (lane + 64 < KCH) ? wpart[lane + 64] : NINF;
    float wm = fmaxf(wa, wb);
    float ba = (lane < KCH) ? bpart[lane] : NINF;
    float bb = (lane + 64 < KCH) ? bpart[lane + 64] : NINF;
    float bmx = fmaxf(ba, bb);
#pragma unroll
    for (int d = 32; d > 0; d >>= 1) {
      um  = fmaxf(um,  __shfl_xor(um,  d, 64));
      wm  = fmaxf(wm,  __shfl_xor(wm,  d, 64));
      bmx = fmaxf(bmx, __shfl_xor(bmx, d, 64));
    }
    if (lane == 0) {
      float lb = gumbel_(um) - bmx;                        // rowmax_key lower bound
      sThr = lb - (2.0f * HBND * wm * 1.001f + 1e-3f) - 2e-3f;
      sBm  = bmx;
    }
  }
  __syncthreads();
  float thr = sThr, bmx = sBm;
  if (tid < KCH && gumbel_(pp[(size_t)r*KCH + tid]) + bmx + 2e-3f >= thr) {
    int i = atomicAdd(&nch, 1);
    chlist[i] = tid;
  }
  __syncthreads();
  int nchunks = nch;
  const float* urow = gu + ((size_t)t*KNS + s)*KN;
  for (int ci = 0; ci < nchunks; ++ci) {
    int base = chlist[ci]*256;
#pragma unroll
    for (int half = 0; half < 2; ++half) {
      int col = base + half*128 + tid;
      if (col < KN) {
        float key = gumbel_(urow[col]) + b_up[col];        // exact key
        if (key >= thr) {
          int i = atomicAdd(&ncand, 1);
          if (i < CMAX) candbuf[(size_t)r*CMAX + i] = make_int2(__float_as_int(key), col);
          else ovf = 1;
        }
      }
    }
  }
  __syncthreads();
  if (tid == 0) candcnt[r] = ovf ? -1 : ncand;
}

// ------- final: block = sample; 8 steps of {best candidate via wave-parallel
//         dot, spike write, LSTM advance}. -------
__global__ void __launch_bounds__(256) k_final(
    const int2* __restrict__ candbuf, const int* __restrict__ candcnt,
    const float* __restrict__ gu,
    const float* __restrict__ W_up, const float* __restrict__ b_up,
    const float* __restrict__ hg, const float* __restrict__ cg,
    const float* __restrict__ W_down,
    const float* __restrict__ w_ih, const float* __restrict__ w_hh,
    const float* __restrict__ b_ih, const float* __restrict__ b_hh,
    float* __restrict__ out) {
  int s = blockIdx.x, tid = threadIdx.x;
  int wave = tid >> 6, lane = tid & 63;
  __shared__ float hs[KH], cs[KH], xs[KDW], g[4*KH];
  __shared__ unsigned long long wbest[4];
  __shared__ int widxS;

  if (tid < KH) { hs[tid] = hg[s*KH + tid]; cs[tid] = cg[s*KH + tid]; }
  __syncthreads();

  for (int t = 0; t < KRW; ++t) {
    int r = s*KRW + t;
    int nc = candcnt[r];
    unsigned long long best = 0ull;
    if (nc >= 0) {
      for (int ci = wave; ci < nc; ci += 4) {
        int2 cd = candbuf[(size_t)r*CMAX + ci];
        float key = __int_as_float(cd.x);
        int col = cd.y;
        float p = (lane < KH) ? hs[lane] * W_up[lane*KN + col] : 0.f;
#pragma unroll
        for (int d = 32; d > 0; d >>= 1) p += __shfl_xor(p, d, 64);
        unsigned long long pk = packsc_(key + p, col);
        if (pk > best) best = pk;
      }
    } else {
      // exact fallback (never expected): full-row rescan
      const float* urow = gu + ((size_t)t*KNS + s)*KN;
      for (int col = tid; col < KN; col += 256) {
        float sc = gumbel_(urow[col]) + b_up[col];
#pragma unroll
        for (int k = 0; k < KH; ++k) sc = fmaf(hs[k], W_up[k*KN + col], sc);
        unsigned long long pk = packsc_(sc, col);
        if (pk > best) best = pk;
      }
    }
#pragma unroll
    for (int d = 32; d > 0; d >>= 1) {
      unsigned long long q = (unsigned long long)__shfl_xor((long long)best, d, 64);
      if (q > best) best = q;
    }
    if (lane == 0) wbest[wave] = best;
    __syncthreads();
    if (tid == 0) {
      unsigned long long fb = wbest[0];
      if (wbest[1] > fb) fb = wbest[1];
      if (wbest[2] > fb) fb = wbest[2];
      if (wbest[3] > fb) fb = wbest[3];
      int w = (int)(~(unsigned)(fb & 0xFFFFFFFFull));
      widxS = w;
      out[((size_t)s*KRW + t)*KN + w] = 1.0f;          // spike (zeros laid by stream)
    }
    __syncthreads();
    if (t < KRW - 1) {
      if (tid < KDW) xs[tid] = W_down[(size_t)widxS*KDW + tid];
      __syncthreads();
      if (tid < 4*KH) {
        float a = b_ih[tid] + b_hh[tid];
#pragma unroll 8
        for (int k = 0; k < KDW; ++k) a = fmaf(xs[k], w_ih[k*4*KH + tid], a);
#pragma unroll 8
        for (int k = 0; k < KH; ++k) a = fmaf(hs[k], w_hh[k*4*KH + tid], a);
        g[tid] = a;
      }
      __syncthreads();
      if (tid < KH) {
        float gi = g[tid], gf = g[KH+tid], gg2 = g[2*KH+tid], go = g[3*KH+tid];
        float cn = sigmoidf_(gf) * cs[tid] + sigmoidf_(gi) * tanhf(gg2);
        float hn_ = sigmoidf_(go) * tanhf(cn);
        hs[tid] = hn_; cs[tid] = cn;
      }
      __syncthreads();
    }
  }
}

extern "C" void kernel_launch(void* const* d_in, const int* in_sizes, int n_in,
                              void* d_out, int out_size, void* d_ws, size_t ws_size,
                              hipStream_t stream) {
  const float* z      = (const float*)d_in[0];
  const float* gu     = (const float*)d_in[1];
  const float* l1w    = (const float*)d_in[2];
  const float* l1b    = (const float*)d_in[3];
  const float* l2w    = (const float*)d_in[4];
  const float* l2b    = (const float*)d_in[5];
  const float* l3w    = (const float*)d_in[6];
  const float* l3b    = (const float*)d_in[7];
  const float* w_ih   = (const float*)d_in[8];
  const float* w_hh   = (const float*)d_in[9];
  const float* b_ih   = (const float*)d_in[10];
  const float* b_hh   = (const float*)d_in[11];
  const float* W_up   = (const float*)d_in[12];
  const float* b_up   = (const float*)d_in[13];
  const float* W_down = (const float*)d_in[14];
  float* out = (float*)d_out;

  // workspace (~2.5 MB), every byte rewritten each call
  char* ws = (char*)d_ws;
  size_t off = 0;
  float* h  = (float*)(ws + off); off += (size_t)KNS*KH*4;
  float* c  = (float*)(ws + off); off += (size_t)KNS*KH*4;
  float* pp = (float*)(ws + off); off += (size_t)NROW*KCH*4;
  float* wpart = (float*)(ws + off); off += 128*4;
  float* bpart = (float*)(ws + off); off += 128*4;
  int2* candbuf = (int2*)(ws + off); off += (size_t)NROW*CMAX*8;
  int* candcnt = (int*)(ws + off);

  k_init_wnorm<<<KNS + KCH, 256, 0, stream>>>(z, l1w, l1b, l2w, l2b, l3w, l3b,
                                              b_ih, b_hh, w_hh, W_up, b_up,
                                              h, c, wpart, bpart);

  k_score_zero<<<KNS*KRW, 1024, (size_t)(KN + 128)*4, stream>>>(gu, pp, out);

  k_cands<<<NROW, 128, 0, stream>>>(pp, gu, b_up, wpart, bpart, candbuf, candcnt);

  k_final<<<KNS, 256, 0, stream>>>(candbuf, candcnt, gu, W_up, b_up, h, c,
                                   W_down, w_ih, w_hh, b_ih, b_hh, out);
}